// Round 13
// baseline (363.979 us; speedup 1.0000x reference)
//
#include <hip/hip_runtime.h>
#include <hip/hip_cooperative_groups.h>
#include <hip/hip_bf16.h>

namespace cg = cooperative_groups;

#define D    64    // feature dim == units
#define CH   4096  // edges per chunk (phases A/C)
#define BKT  32    // nodes per bucket (phase D)
#define PASS 1024  // edges staged per pass in phase D
#define SU   2048  // scan unit (phase B); SU = 1<<11

// One cooperative kernel, 4 phases separated by grid.sync():
//  A: Z = emb@W (bf16) + per-chunk bucket histogram (LDS int atomics) + ranks
//  B: two-level exclusive scan of the bucket-major histogram (coalesced)
//  C: bucket-grouped scatter of edge records (LDS-staged, no atomics)
//  D: per-bucket sort-by-node in LDS + register gather + relu store
__global__ __launch_bounds__(256, 2) void fused(
    const float* __restrict__ emb,
    const float* __restrict__ W,
    const int*   __restrict__ esrc,
    const int*   __restrict__ edst,
    const float* __restrict__ ew,
    float*       __restrict__ out,
    __hip_bfloat16* __restrict__ Zb,
    int*    __restrict__ histG,     // [Mpad] bucket-major: m = b*NC + c
    int*    __restrict__ offsets,   // [Mpad] per-unit exclusive scan
    int*    __restrict__ partials,  // [<=256] unit totals -> exclusive prefix
    ushort* __restrict__ lrank,     // [E]
    int2*   __restrict__ csr,       // [E] {src | (dst%32)<<16, w_bits}
    int N, int E, int NB, int NC, int M, int units, int gemmTiles)
{
    __shared__ __align__(16) char smem[49152];   // 48 KB -> 3 blocks/CU by LDS
    cg::grid_group grid = cg::this_grid();
    const int t = threadIdx.x;
    const int G = gridDim.x;

    // ---------------- Phase A: GEMM tiles + histogram chunks ---------------
    for (int it = blockIdx.x; it < gemmTiles + NC; it += G) {
        __syncthreads();   // smem reuse across work items
        if (it < gemmTiles) {
            float* At = (float*)smem;            // 64x64 tile (16 KB)
            const int lane = t & 63, wave = t >> 6;
            float wcol[D];
#pragma unroll
            for (int k = 0; k < D; ++k) wcol[k] = W[k * D + lane];
            const int row0 = it * 64;
            for (int i = t; i < 1024; i += 256) {
                int r = i >> 4, gr = row0 + r;
                float4 v = (gr < N)
                    ? reinterpret_cast<const float4*>(emb)[(size_t)gr * 16 + (i & 15)]
                    : float4{0.f, 0.f, 0.f, 0.f};
                reinterpret_cast<float4*>(At)[i] = v;
            }
            __syncthreads();
            for (int rr = 0; rr < 16; ++rr) {
                int r = wave * 16 + rr, gr = row0 + r;
                if (gr >= N) break;
                const float4* arow = reinterpret_cast<const float4*>(At + r * D);
                float acc = 0.f;
#pragma unroll
                for (int k4 = 0; k4 < 16; ++k4) {
                    float4 a = arow[k4];
                    acc = fmaf(a.x, wcol[4 * k4 + 0], acc);
                    acc = fmaf(a.y, wcol[4 * k4 + 1], acc);
                    acc = fmaf(a.z, wcol[4 * k4 + 2], acc);
                    acc = fmaf(a.w, wcol[4 * k4 + 3], acc);
                }
                Zb[(size_t)gr * D + lane] = __float2bfloat16(acc);
            }
        } else {
            const int c = it - gemmTiles;
            int* hist = (int*)smem;              // NB ints (<= 6.3 KB)
            for (int b = t; b < NB; b += 256) hist[b] = 0;
            __syncthreads();
            const int e0 = c * CH;
#pragma unroll
            for (int i = 0; i < 16; ++i) {
                int e = e0 + i * 256 + t;
                if (e < E)
                    lrank[e] = (ushort)atomicAdd(&hist[edst[e] >> 5], 1);  // ds_add_rtn
            }
            __syncthreads();
            for (int b = t; b < NB; b += 256)
                histG[(size_t)b * NC + c] = hist[b];   // bucket-major, fire-and-forget
        }
    }
    grid.sync();

    // ---------------- Phase B1: per-unit exclusive scan (coalesced) --------
    for (int u = blockIdx.x; u < units; u += G) {
        __syncthreads();
        int* sh = (int*)smem;
        const int base = u * SU + t * 8;
        int v[8], ps[8];
#pragma unroll
        for (int k = 0; k < 8; ++k) {
            int m = base + k;
            v[k] = (m < M) ? histG[m] : 0;   // pad reads 0 (pad never written)
        }
        int s = 0;
#pragma unroll
        for (int k = 0; k < 8; ++k) { ps[k] = s; s += v[k]; }
        sh[t] = s;
        __syncthreads();
        for (int off = 1; off < 256; off <<= 1) {
            int x = (t >= off) ? sh[t - off] : 0;
            __syncthreads();
            sh[t] += x;
            __syncthreads();
        }
        const int excl = sh[t] - s;
#pragma unroll
        for (int k = 0; k < 8; ++k)
            offsets[base + k] = excl + ps[k];
        if (t == 255) partials[u] = sh[255];
    }
    grid.sync();

    // ---------------- Phase B2: scan the <=256 unit totals (block 0) -------
    if (blockIdx.x == 0) {
        int* sh = (int*)smem;
        int orig = (t < units) ? partials[t] : 0;
        sh[t] = orig;
        __syncthreads();
        for (int off = 1; off < 256; off <<= 1) {
            int x = (t >= off) ? sh[t - off] : 0;
            __syncthreads();
            sh[t] += x;
            __syncthreads();
        }
        if (t < units) partials[t] = sh[t] - orig;   // exclusive prefix
    }
    grid.sync();

    // ---------------- Phase C: bucket-grouped scatter ----------------------
    {
        int2*   rec  = (int2*)smem;                // CH x 8 B = 32 KB
        ushort* bidv = (ushort*)(smem + 32768);    // CH x 2 B =  8 KB
        int*    lcnt = (int*)(smem + 40960);       // 1568 ints
        int*    sh   = (int*)(smem + 47232);       // 256 ints
        for (int c = blockIdx.x; c < NC; c += G) {
            __syncthreads();
            const int e0  = c * CH;
            const int cnt = min(CH, E - e0);
            for (int b = t; b < NB; b += 256) lcnt[b] = 0;
            __syncthreads();
#pragma unroll
            for (int i = 0; i < 16; ++i) {
                int e = e0 + i * 256 + t;
                if (e < E) atomicAdd(&lcnt[edst[e] >> 5], 1);   // recount (no return)
            }
            __syncthreads();
            // local exclusive scan of lcnt (7 buckets/thread)
            int hv[7], ps[7];
            const int hbase = t * 7;
#pragma unroll
            for (int k = 0; k < 7; ++k) {
                int b = hbase + k;
                hv[k] = (b < NB) ? lcnt[b] : 0;
            }
            int s = 0;
#pragma unroll
            for (int k = 0; k < 7; ++k) { ps[k] = s; s += hv[k]; }
            sh[t] = s;
            __syncthreads();
            for (int off = 1; off < 256; off <<= 1) {
                int x = (t >= off) ? sh[t - off] : 0;
                __syncthreads();
                sh[t] += x;
                __syncthreads();
            }
            const int hexcl = sh[t] - s;
#pragma unroll
            for (int k = 0; k < 7; ++k) {
                int b = hbase + k;
                if (b < NB) lcnt[b] = hexcl + ps[k];   // localBase
            }
            __syncthreads();
            // stage records sorted by bucket
#pragma unroll
            for (int i = 0; i < 16; ++i) {
                int e = e0 + i * 256 + t;
                if (e < E) {
                    int d  = edst[e];
                    int b  = d >> 5;
                    int lp = lcnt[b] + lrank[e];
                    rec[lp]  = make_int2(esrc[e] | ((d & 31) << 16), __float_as_int(ew[e]));
                    bidv[lp] = (ushort)b;
                }
            }
            __syncthreads();
            // lcnt[b] := globalChunkOff - localBase
#pragma unroll
            for (int k = 0; k < 7; ++k) {
                int b = hbase + k;
                if (b < NB) {
                    int m = b * NC + c;
                    lcnt[b] = offsets[m] + partials[m >> 11] - lcnt[b];
                }
            }
            __syncthreads();
            for (int j = t; j < cnt; j += 256)
                csr[j + lcnt[bidv[j]]] = rec[j];
        }
    }
    grid.sync();

    // ---------------- Phase D: per-bucket aggregate ------------------------
    {
        int2* srec  = (int2*)smem;                 // PASS x 8 B = 8 KB
        int*  hist  = (int*)(smem + 8192);         // BKT
        int*  nbase = (int*)(smem + 8192 + 128);   // BKT + 1
        const int wv = t >> 6, lane = t & 63, slot = lane >> 3, q = lane & 7;
        const int4* Zq = reinterpret_cast<const int4*>(Zb);   // bf16 row = 8 int4

        for (int b = blockIdx.x; b < NB; b += G) {
            __syncthreads();
            const int m0 = b * NC, m1 = m0 + NC;   // m1 <= M < Mpad: valid
            const int bStart = offsets[m0] + partials[m0 >> 11];
            const int bEnd   = offsets[m1] + partials[m1 >> 11];

            float4 alo[8], ahi[8];
#pragma unroll
            for (int r = 0; r < 8; ++r) { alo[r] = float4{0,0,0,0}; ahi[r] = float4{0,0,0,0}; }

            for (int cur = bStart; cur < bEnd; cur += PASS) {
                const int cnt = min(PASS, bEnd - cur);
                if (t < BKT) hist[t] = 0;
                __syncthreads();
                int2 myrec[4]; int mypos[4];
#pragma unroll
                for (int k = 0; k < 4; ++k) {
                    int j = k * 256 + t;
                    if (j < cnt) {
                        int2 r2 = csr[cur + j];
                        myrec[k] = r2;
                        mypos[k] = atomicAdd(&hist[(r2.x >> 16) & (BKT - 1)], 1);
                    }
                }
                __syncthreads();
                if (t < BKT) {
                    int v = hist[t], x = v;
                    for (int off = 1; off < BKT; off <<= 1) {
                        int y = __shfl_up(x, off, 64);
                        if (t >= off) x += y;
                    }
                    nbase[t] = x - v;
                    if (t == BKT - 1) nbase[BKT] = x;
                }
                __syncthreads();
#pragma unroll
                for (int k = 0; k < 4; ++k) {
                    int j = k * 256 + t;
                    if (j < cnt)
                        srec[nbase[(myrec[k].x >> 16) & (BKT - 1)] + mypos[k]] = myrec[k];
                }
                __syncthreads();
                for (int r = 0; r < 8; ++r) {
                    const int nl = wv * 8 + r;
                    const int je = nbase[nl + 1];
                    for (int j = nbase[nl] + slot; j < je; j += 8) {
                        int2  e  = srec[j];
                        float ww = __int_as_float(e.y);
                        int   sn = e.x & 0xFFFF;
                        int4  zz = Zq[(size_t)sn * 8 + q];
                        alo[r].x = fmaf(ww, __uint_as_float((unsigned)zz.x << 16),         alo[r].x);
                        alo[r].y = fmaf(ww, __uint_as_float((unsigned)zz.x & 0xFFFF0000u), alo[r].y);
                        alo[r].z = fmaf(ww, __uint_as_float((unsigned)zz.y << 16),         alo[r].z);
                        alo[r].w = fmaf(ww, __uint_as_float((unsigned)zz.y & 0xFFFF0000u), alo[r].w);
                        ahi[r].x = fmaf(ww, __uint_as_float((unsigned)zz.z << 16),         ahi[r].x);
                        ahi[r].y = fmaf(ww, __uint_as_float((unsigned)zz.z & 0xFFFF0000u), ahi[r].y);
                        ahi[r].z = fmaf(ww, __uint_as_float((unsigned)zz.w << 16),         ahi[r].z);
                        ahi[r].w = fmaf(ww, __uint_as_float((unsigned)zz.w & 0xFFFF0000u), ahi[r].w);
                    }
                }
                __syncthreads();
            }

            const int node0 = b * BKT + wv * 8;
#pragma unroll
            for (int r = 0; r < 8; ++r) {
                float4 lo = alo[r], hi = ahi[r];
#pragma unroll
                for (int off = 32; off >= 8; off >>= 1) {
                    lo.x += __shfl_down(lo.x, off, 64);
                    lo.y += __shfl_down(lo.y, off, 64);
                    lo.z += __shfl_down(lo.z, off, 64);
                    lo.w += __shfl_down(lo.w, off, 64);
                    hi.x += __shfl_down(hi.x, off, 64);
                    hi.y += __shfl_down(hi.y, off, 64);
                    hi.z += __shfl_down(hi.z, off, 64);
                    hi.w += __shfl_down(hi.w, off, 64);
                }
                int node = node0 + r;
                if (lane < 8 && node < N) {
                    float4 o0, o1;
                    o0.x = fmaxf(lo.x, 0.f); o0.y = fmaxf(lo.y, 0.f);
                    o0.z = fmaxf(lo.z, 0.f); o0.w = fmaxf(lo.w, 0.f);
                    o1.x = fmaxf(hi.x, 0.f); o1.y = fmaxf(hi.y, 0.f);
                    o1.z = fmaxf(hi.z, 0.f); o1.w = fmaxf(hi.w, 0.f);
                    float4* orow = reinterpret_cast<float4*>(out) + (size_t)node * 16 + lane * 2;
                    orow[0] = o0;
                    orow[1] = o1;
                }
            }
        }
    }
}

// ---------------------------------------------------------------------------
extern "C" void kernel_launch(void* const* d_in, const int* in_sizes, int n_in,
                              void* d_out, int out_size, void* d_ws, size_t ws_size,
                              hipStream_t stream)
{
    const float* emb  = (const float*)d_in[0];  // [N, 64]
    const int*   esrc = (const int*)  d_in[1];  // [E]
    const int*   edst = (const int*)  d_in[2];  // [E]
    const float* ew   = (const float*)d_in[3];  // [E]
    const float* W    = (const float*)d_in[4];  // [64, 64]
    float*       out  = (float*)d_out;          // [N, 64]

    const int N  = in_sizes[0] / D;
    const int E  = in_sizes[1];

    const int NB    = (N + BKT - 1) / BKT;     // 1563 buckets
    const int NC    = (E + CH - 1) / CH;       // 196 chunks
    const int M     = NB * NC;                 // 306,348
    const int units = (M + SU - 1) / SU;       // 150 <= 256
    const int Mpad  = units * SU;
    const int gemmTiles = (N + 63) / 64;       // 782

    // Workspace (~16.9 MB), all segments 16 B aligned.
    char* p = (char*)d_ws;
    __hip_bfloat16* Zb = (__hip_bfloat16*)p;  p += (size_t)N * D * 2;        // 6.4 MB
    int*    histG    = (int*)p;               p += (size_t)Mpad * 4;         // 1.2 MB
    int*    offsets  = (int*)p;               p += (size_t)Mpad * 4;         // 1.2 MB
    int*    partials = (int*)p;               p += 256 * 4;
    ushort* lrank    = (ushort*)p;            p += (size_t)((E + 7) & ~7) * 2; // 1.6 MB
    int2*   csr      = (int2*)p;                                             // 6.4 MB

    // Cooperative grid: max co-resident blocks (LDS 48 KB -> expect 3/CU).
    int bpc = 0;
    if (hipOccupancyMaxActiveBlocksPerMultiprocessor(&bpc, fused, 256, 0) != hipSuccess
        || bpc < 1)
        bpc = 2;
    int grid = bpc * 256;              // 256 CUs on MI355X
    if (grid > 2048) grid = 2048;

    int n = N, e = E, nb = NB, nc = NC, m = M, un = units, gt = gemmTiles;
    void* args[] = { (void*)&emb, (void*)&W, (void*)&esrc, (void*)&edst, (void*)&ew,
                     (void*)&out, (void*)&Zb, (void*)&histG, (void*)&offsets,
                     (void*)&partials, (void*)&lrank, (void*)&csr,
                     &n, &e, &nb, &nc, &m, &un, &gt };
    hipLaunchCooperativeKernel(fused, dim3(grid), dim3(256), args, 0, stream);
}

// Round 14
// 139.285 us; speedup vs baseline: 2.6132x; 2.6132x over previous
//
#include <hip/hip_runtime.h>
#include <hip/hip_bf16.h>

#define D    64    // feature dim == units
#define CH   4096  // edges per chunk (K1/K3)
#define BKT  32    // nodes per bucket (K4)
#define PASS 1024  // edges staged per pass in K4
#define SU   2048  // scan unit size (K2)

// ---------------------------------------------------------------------------
// K1: blocks [0, gemmTiles): Z = emb @ W (bf16 out).  Blocks [gemmTiles, +NC):
// per-chunk bucket histogram (LDS int atomics, no return), written BUCKET-
// MAJOR (histG[b*NC+c], scattered 4B fire-and-forget) so K2 reads coalesced.
// ---------------------------------------------------------------------------
__global__ __launch_bounds__(256) void gemm_part(
    const float* __restrict__ emb,
    const float* __restrict__ W,
    __hip_bfloat16* __restrict__ Zb,
    const int*   __restrict__ dst,
    int*         __restrict__ histG,   // [NB * NC], bucket-major
    int N, int E, int NB, int NC, int gemmTiles)
{
    __shared__ int smem[4096];   // hist[NB<=1563] or 64x64 gemm tile

    if ((int)blockIdx.x >= gemmTiles) {
        const int c   = (int)blockIdx.x - gemmTiles;
        const int t   = threadIdx.x;
        const int e0  = c * CH;
        const int cnt = min(CH, E - e0);          // multiple of 4 (E%4==0)
        for (int b = t; b < NB; b += 256) smem[b] = 0;
        __syncthreads();
        const int4* d4p = reinterpret_cast<const int4*>(dst + e0);
#pragma unroll
        for (int i = 0; i < 4; ++i) {
            int g = i * 256 + t;
            if (g * 4 < cnt) {
                int4 d4 = d4p[g];
                atomicAdd(&smem[d4.x >> 5], 1);
                atomicAdd(&smem[d4.y >> 5], 1);
                atomicAdd(&smem[d4.z >> 5], 1);
                atomicAdd(&smem[d4.w >> 5], 1);
            }
        }
        __syncthreads();
        for (int b = t; b < NB; b += 256)
            histG[(size_t)b * NC + c] = smem[b];
        return;
    }

    const int lane = threadIdx.x & 63;
    const int wave = threadIdx.x >> 6;

    float wcol[D];
#pragma unroll
    for (int k = 0; k < D; ++k) wcol[k] = W[k * D + lane];

    float* At = (float*)smem;
    const int row0 = blockIdx.x * 64;

    for (int i = threadIdx.x; i < 1024; i += 256) {
        int r = i >> 4, gr = row0 + r;
        float4 v = (gr < N)
            ? reinterpret_cast<const float4*>(emb)[(size_t)gr * 16 + (i & 15)]
            : float4{0.f, 0.f, 0.f, 0.f};
        reinterpret_cast<float4*>(At)[i] = v;
    }
    __syncthreads();

    for (int rr = 0; rr < 16; ++rr) {
        int r = wave * 16 + rr, gr = row0 + r;
        if (gr >= N) break;
        const float4* arow = reinterpret_cast<const float4*>(At + r * D);
        float acc = 0.f;
#pragma unroll
        for (int k4 = 0; k4 < 16; ++k4) {
            float4 a = arow[k4];
            acc = fmaf(a.x, wcol[4 * k4 + 0], acc);
            acc = fmaf(a.y, wcol[4 * k4 + 1], acc);
            acc = fmaf(a.z, wcol[4 * k4 + 2], acc);
            acc = fmaf(a.w, wcol[4 * k4 + 3], acc);
        }
        Zb[(size_t)gr * D + lane] = __float2bfloat16(acc);
    }
}

// ---------------------------------------------------------------------------
// K2: per-unit exclusive scan of bucket-major histG — fully COALESCED.
// SU=2048 elems/block (256 thr x 8); unit totals to partials (<=256).
// ---------------------------------------------------------------------------
__global__ __launch_bounds__(256) void scan_hist(
    const int* __restrict__ histG, int* __restrict__ offsets,
    int* __restrict__ partials, int M)
{
    __shared__ int sh[256];
    const int t    = threadIdx.x;
    const int base = blockIdx.x * SU + t * 8;

    int v[8], ps[8];
#pragma unroll
    for (int k = 0; k < 8; ++k) {
        int m = base + k;
        v[k] = (m < M) ? histG[m] : 0;
    }
    int s = 0;
#pragma unroll
    for (int k = 0; k < 8; ++k) { ps[k] = s; s += v[k]; }
    sh[t] = s;
    __syncthreads();
    for (int off = 1; off < 256; off <<= 1) {
        int x = (t >= off) ? sh[t - off] : 0;
        __syncthreads();
        sh[t] += x;
        __syncthreads();
    }
    const int excl = sh[t] - s;
#pragma unroll
    for (int k = 0; k < 8; ++k)
        offsets[base + k] = excl + ps[k];
    if (t == 255) partials[blockIdx.x] = sh[255];
}

__device__ __forceinline__ void scan_partials_lds256(
    const int* __restrict__ partials, int nu, int* sp)
{
    const int t    = threadIdx.x;
    const int orig = (t < nu) ? partials[t] : 0;
    sp[t] = orig;
    __syncthreads();
    for (int off = 1; off < 256; off <<= 1) {
        int x = (t >= off) ? sp[t - off] : 0;
        __syncthreads();
        sp[t] += x;
        __syncthreads();
    }
    int incl = sp[t];
    __syncthreads();
    sp[t] = incl - orig;  // exclusive
    __syncthreads();
}

// ---------------------------------------------------------------------------
// K3: bucket-grouped scatter.  Recounts its chunk with ds_add_rtn (no lrank,
// no histG read), stages records sorted by bucket in LDS, writes runs.
// rec.x = src(16) | dl(5)<<16 | bkt(11)<<21   (N<65536, NB<2048).
// ---------------------------------------------------------------------------
__global__ __launch_bounds__(256) void scatter_bkt(
    const int*   __restrict__ src,
    const int*   __restrict__ dst,
    const float* __restrict__ w,
    const int*   __restrict__ offsets,
    const int*   __restrict__ partials,
    int2*        __restrict__ csr,
    int E, int NB, int NC, int units)
{
    __shared__ int2 rec[CH];       // 32 KB
    __shared__ int  lcnt[1568];    // 6.3 KB
    __shared__ int  sh[256];
    __shared__ int  sp[256];
    scan_partials_lds256(partials, units, sp);

    const int t   = threadIdx.x;
    const int c   = blockIdx.x;
    const int e0  = c * CH;
    const int cnt = min(CH, E - e0);   // multiple of 4

    for (int b = t; b < NB; b += 256) lcnt[b] = 0;
    __syncthreads();

    // load + count-with-return (16 edges/thread, vector loads)
    int2 myrec[16]; int mypos[16];
    const int4*   s4p = reinterpret_cast<const int4*>(src + e0);
    const int4*   d4p = reinterpret_cast<const int4*>(dst + e0);
    const float4* w4p = reinterpret_cast<const float4*>(w + e0);
#pragma unroll
    for (int i = 0; i < 4; ++i) {
        int g = i * 256 + t;
        if (g * 4 < cnt) {
            int4   s4 = s4p[g];
            int4   d4 = d4p[g];
            float4 w4 = w4p[g];
            int b0 = d4.x >> 5, b1 = d4.y >> 5, b2 = d4.z >> 5, b3 = d4.w >> 5;
            myrec[4*i+0] = make_int2(s4.x | ((d4.x & 31) << 16) | (b0 << 21), __float_as_int(w4.x));
            myrec[4*i+1] = make_int2(s4.y | ((d4.y & 31) << 16) | (b1 << 21), __float_as_int(w4.y));
            myrec[4*i+2] = make_int2(s4.z | ((d4.z & 31) << 16) | (b2 << 21), __float_as_int(w4.z));
            myrec[4*i+3] = make_int2(s4.w | ((d4.w & 31) << 16) | (b3 << 21), __float_as_int(w4.w));
            mypos[4*i+0] = atomicAdd(&lcnt[b0], 1);
            mypos[4*i+1] = atomicAdd(&lcnt[b1], 1);
            mypos[4*i+2] = atomicAdd(&lcnt[b2], 1);
            mypos[4*i+3] = atomicAdd(&lcnt[b3], 1);
        } else {
#pragma unroll
            for (int k = 0; k < 4; ++k) mypos[4*i+k] = -1;
        }
    }
    __syncthreads();

    // local exclusive scan of lcnt (7 buckets/thread covers 1792 >= NB)
    int hv[7], ps[7];
    const int hbase = t * 7;
#pragma unroll
    for (int k = 0; k < 7; ++k) {
        int b = hbase + k;
        hv[k] = (b < NB) ? lcnt[b] : 0;
    }
    int s = 0;
#pragma unroll
    for (int k = 0; k < 7; ++k) { ps[k] = s; s += hv[k]; }
    sh[t] = s;
    __syncthreads();
    for (int off = 1; off < 256; off <<= 1) {
        int x = (t >= off) ? sh[t - off] : 0;
        __syncthreads();
        sh[t] += x;
        __syncthreads();
    }
    const int hexcl = sh[t] - s;
    __syncthreads();                       // all reads of lcnt done
#pragma unroll
    for (int k = 0; k < 7; ++k) {
        int b = hbase + k;
        if (b < NB) lcnt[b] = hexcl + ps[k];   // localBase
    }
    __syncthreads();

    // stage records sorted by bucket
#pragma unroll
    for (int k = 0; k < 16; ++k) {
        if (mypos[k] >= 0)
            rec[lcnt[(unsigned)myrec[k].x >> 21] + mypos[k]] = myrec[k];
    }
    __syncthreads();

    // lcnt[b] := globalChunkOff(b,c) - localBase[b]
#pragma unroll
    for (int k = 0; k < 7; ++k) {
        int b = hbase + k;
        if (b < NB) {
            int m = b * NC + c;
            lcnt[b] = offsets[m] + sp[m >> 11] - lcnt[b];
        }
    }
    __syncthreads();

    for (int j = t; j < cnt; j += 256) {
        int2 rj = rec[j];
        csr[j + lcnt[(unsigned)rj.x >> 21]] = rj;
    }
}

// ---------------------------------------------------------------------------
// K4: one block per 32-node bucket.  Sort pass edges by node in LDS (int
// atomics + shfl scan), then register-gather with an explicit 3-DEEP PREFETCH
// per slot (covers deg<=24, P~98%; tail loop beyond): three independent
// Z-row loads issue before any waitcnt -> 24 outstanding loads per wave.
// ---------------------------------------------------------------------------
__global__ __launch_bounds__(256) void aggregate(
    const __hip_bfloat16* __restrict__ Zb,
    const int2* __restrict__ csr,
    const int*  __restrict__ offsets,
    const int*  __restrict__ partials,
    float*      __restrict__ out,
    int N, int NB, int NC, int units)
{
    __shared__ int2 srec[PASS];   // 8 KB
    __shared__ int  hist[BKT];
    __shared__ int  nbase[BKT + 1];
    __shared__ int  sp[256];
    scan_partials_lds256(partials, units, sp);

    const int t = threadIdx.x;
    const int b = blockIdx.x;

    const int m0 = b * NC, m1 = m0 + NC;
    const int bStart = offsets[m0] + sp[m0 >> 11];
    const int bEnd   = offsets[m1] + sp[m1 >> 11];

    const int wv = t >> 6, lane = t & 63, slot = lane >> 3, q = lane & 7;
    const int4* Zq = reinterpret_cast<const int4*>(Zb);   // bf16 row = 8 int4

    float4 alo[8], ahi[8];
#pragma unroll
    for (int r = 0; r < 8; ++r) { alo[r] = float4{0,0,0,0}; ahi[r] = float4{0,0,0,0}; }

#define FMA8(LO, HI, WW, ZZ)                                                     \
    do {                                                                         \
        (LO).x = fmaf((WW), __uint_as_float((unsigned)(ZZ).x << 16),        (LO).x); \
        (LO).y = fmaf((WW), __uint_as_float((unsigned)(ZZ).x & 0xFFFF0000u),(LO).y); \
        (LO).z = fmaf((WW), __uint_as_float((unsigned)(ZZ).y << 16),        (LO).z); \
        (LO).w = fmaf((WW), __uint_as_float((unsigned)(ZZ).y & 0xFFFF0000u),(LO).w); \
        (HI).x = fmaf((WW), __uint_as_float((unsigned)(ZZ).z << 16),        (HI).x); \
        (HI).y = fmaf((WW), __uint_as_float((unsigned)(ZZ).z & 0xFFFF0000u),(HI).y); \
        (HI).z = fmaf((WW), __uint_as_float((unsigned)(ZZ).w << 16),        (HI).z); \
        (HI).w = fmaf((WW), __uint_as_float((unsigned)(ZZ).w & 0xFFFF0000u),(HI).w); \
    } while (0)

    for (int cur = bStart; cur < bEnd; cur += PASS) {
        const int cnt = min(PASS, bEnd - cur);
        if (t < BKT) hist[t] = 0;
        __syncthreads();

        int2 myrec[4]; int mypos[4];
#pragma unroll
        for (int k = 0; k < 4; ++k) {
            int j = k * 256 + t;
            if (j < cnt) {
                int2 r2 = csr[cur + j];
                myrec[k] = r2;
                mypos[k] = atomicAdd(&hist[(r2.x >> 16) & (BKT - 1)], 1);
            } else mypos[k] = -1;
        }
        __syncthreads();

        if (t < BKT) {
            int v = hist[t], x = v;
            for (int off = 1; off < BKT; off <<= 1) {
                int y = __shfl_up(x, off, 64);
                if (t >= off) x += y;
            }
            nbase[t] = x - v;
            if (t == BKT - 1) nbase[BKT] = x;
        }
        __syncthreads();

#pragma unroll
        for (int k = 0; k < 4; ++k) {
            if (mypos[k] >= 0)
                srec[nbase[(myrec[k].x >> 16) & (BKT - 1)] + mypos[k]] = myrec[k];
        }
        __syncthreads();

        // gather: wave wv owns nodes [wv*8, wv*8+8), 3-deep prefetched
        for (int r = 0; r < 8; ++r) {
            const int nl = wv * 8 + r;
            const int jb = nbase[nl] + slot;
            const int je = nbase[nl + 1];
            const int j1 = jb + 8, j2 = jb + 16;
            int2 e0 = make_int2(0, 0), e1 = make_int2(0, 0), e2 = make_int2(0, 0);
            if (jb < je) e0 = srec[jb];
            if (j1 < je) e1 = srec[j1];
            if (j2 < je) e2 = srec[j2];
            int4 z0 = make_int4(0,0,0,0), z1 = make_int4(0,0,0,0), z2 = make_int4(0,0,0,0);
            if (jb < je) z0 = Zq[(size_t)(e0.x & 0xFFFF) * 8 + q];
            if (j1 < je) z1 = Zq[(size_t)(e1.x & 0xFFFF) * 8 + q];
            if (j2 < je) z2 = Zq[(size_t)(e2.x & 0xFFFF) * 8 + q];
            FMA8(alo[r], ahi[r], __int_as_float(e0.y), z0);
            FMA8(alo[r], ahi[r], __int_as_float(e1.y), z1);
            FMA8(alo[r], ahi[r], __int_as_float(e2.y), z2);
            for (int j = j2 + 8; j < je; j += 8) {    // tail (deg > 24)
                int2 e = srec[j];
                int4 zz = Zq[(size_t)(e.x & 0xFFFF) * 8 + q];
                FMA8(alo[r], ahi[r], __int_as_float(e.y), zz);
            }
        }
        __syncthreads();
    }

    // reduce the 8 slots + store (8 lanes x 32 B = coalesced 256 B row)
    const int node0 = b * BKT + wv * 8;
#pragma unroll
    for (int r = 0; r < 8; ++r) {
        float4 lo = alo[r], hi = ahi[r];
#pragma unroll
        for (int off = 32; off >= 8; off >>= 1) {
            lo.x += __shfl_down(lo.x, off, 64);
            lo.y += __shfl_down(lo.y, off, 64);
            lo.z += __shfl_down(lo.z, off, 64);
            lo.w += __shfl_down(lo.w, off, 64);
            hi.x += __shfl_down(hi.x, off, 64);
            hi.y += __shfl_down(hi.y, off, 64);
            hi.z += __shfl_down(hi.z, off, 64);
            hi.w += __shfl_down(hi.w, off, 64);
        }
        int node = node0 + r;
        if (lane < 8 && node < N) {
            float4 o0, o1;
            o0.x = fmaxf(lo.x, 0.f); o0.y = fmaxf(lo.y, 0.f);
            o0.z = fmaxf(lo.z, 0.f); o0.w = fmaxf(lo.w, 0.f);
            o1.x = fmaxf(hi.x, 0.f); o1.y = fmaxf(hi.y, 0.f);
            o1.z = fmaxf(hi.z, 0.f); o1.w = fmaxf(hi.w, 0.f);
            float4* orow = reinterpret_cast<float4*>(out) + (size_t)node * 16 + lane * 2;
            orow[0] = o0;
            orow[1] = o1;
        }
    }
#undef FMA8
}

// ---------------------------------------------------------------------------
extern "C" void kernel_launch(void* const* d_in, const int* in_sizes, int n_in,
                              void* d_out, int out_size, void* d_ws, size_t ws_size,
                              hipStream_t stream)
{
    const float* emb  = (const float*)d_in[0];  // [N, 64]
    const int*   esrc = (const int*)  d_in[1];  // [E]
    const int*   edst = (const int*)  d_in[2];  // [E]
    const float* ew   = (const float*)d_in[3];  // [E]
    const float* W    = (const float*)d_in[4];  // [64, 64]
    float*       out  = (float*)d_out;          // [N, 64]

    const int N = in_sizes[0] / D;
    const int E = in_sizes[1];

    const int NB    = (N + BKT - 1) / BKT;   // 1563 buckets
    const int NC    = (E + CH - 1) / CH;     // 196 chunks
    const int M     = NB * NC;               // 306,348
    const int units = (M + SU - 1) / SU;     // 150 <= 256
    const int Mpad  = units * SU;
    const int gemmTiles = (N + 63) / 64;     // 782

    // Workspace (~15.2 MB), all segments 16 B aligned.
    char* p = (char*)d_ws;
    __hip_bfloat16* Zb = (__hip_bfloat16*)p;  p += (size_t)N * D * 2;   // 6.4 MB
    int*  histG    = (int*)p;                 p += (size_t)Mpad * 4;    // 1.2 MB
    int*  offsets  = (int*)p;                 p += (size_t)Mpad * 4;    // 1.2 MB
    int*  partials = (int*)p;                 p += 256 * 4;
    int2* csr      = (int2*)p;                                          // 6.4 MB

    gemm_part<<<gemmTiles + NC, 256, 0, stream>>>(
        emb, W, Zb, edst, histG, N, E, NB, NC, gemmTiles);

    scan_hist<<<units, 256, 0, stream>>>(histG, offsets, partials, M);

    scatter_bkt<<<NC, 256, 0, stream>>>(
        esrc, edst, ew, offsets, partials, csr, E, NB, NC, units);

    aggregate<<<NB, 256, 0, stream>>>(
        Zb, csr, offsets, partials, out, N, NB, NC, units);
}

// Round 15
// 137.094 us; speedup vs baseline: 2.6550x; 1.0160x over previous
//
#include <hip/hip_runtime.h>
#include <hip/hip_bf16.h>

#define D    64    // feature dim == units
#define CH   4096  // edges per chunk (K1/K3)
#define BKT  32    // nodes per bucket (K4)
#define PASS 1024  // edges staged per pass in K4
#define SU   2048  // scan unit size (K2)

// ---------------------------------------------------------------------------
// K1: blocks [0, gemmTiles): Z = emb @ W (bf16 out).  Blocks [gemmTiles, +NC):
// per-chunk bucket histogram (LDS int atomics, no return), written BUCKET-
// MAJOR (histG[b*NC+c], scattered 4B fire-and-forget) so K2 reads coalesced.
// ---------------------------------------------------------------------------
__global__ __launch_bounds__(256) void gemm_part(
    const float* __restrict__ emb,
    const float* __restrict__ W,
    __hip_bfloat16* __restrict__ Zb,
    const int*   __restrict__ dst,
    int*         __restrict__ histG,   // [NB * NC], bucket-major
    int N, int E, int NB, int NC, int gemmTiles)
{
    __shared__ int smem[4096];   // hist[NB<=1563] or 64x64 gemm tile

    if ((int)blockIdx.x >= gemmTiles) {
        const int c   = (int)blockIdx.x - gemmTiles;
        const int t   = threadIdx.x;
        const int e0  = c * CH;
        const int cnt = min(CH, E - e0);          // multiple of 4 (E%4==0)
        for (int b = t; b < NB; b += 256) smem[b] = 0;
        __syncthreads();
        const int4* d4p = reinterpret_cast<const int4*>(dst + e0);
#pragma unroll
        for (int i = 0; i < 4; ++i) {
            int g = i * 256 + t;
            if (g * 4 < cnt) {
                int4 d4 = d4p[g];
                atomicAdd(&smem[d4.x >> 5], 1);
                atomicAdd(&smem[d4.y >> 5], 1);
                atomicAdd(&smem[d4.z >> 5], 1);
                atomicAdd(&smem[d4.w >> 5], 1);
            }
        }
        __syncthreads();
        for (int b = t; b < NB; b += 256)
            histG[(size_t)b * NC + c] = smem[b];
        return;
    }

    const int lane = threadIdx.x & 63;
    const int wave = threadIdx.x >> 6;

    float wcol[D];
#pragma unroll
    for (int k = 0; k < D; ++k) wcol[k] = W[k * D + lane];

    float* At = (float*)smem;
    const int row0 = blockIdx.x * 64;

    for (int i = threadIdx.x; i < 1024; i += 256) {
        int r = i >> 4, gr = row0 + r;
        float4 v = (gr < N)
            ? reinterpret_cast<const float4*>(emb)[(size_t)gr * 16 + (i & 15)]
            : float4{0.f, 0.f, 0.f, 0.f};
        reinterpret_cast<float4*>(At)[i] = v;
    }
    __syncthreads();

    for (int rr = 0; rr < 16; ++rr) {
        int r = wave * 16 + rr, gr = row0 + r;
        if (gr >= N) break;
        const float4* arow = reinterpret_cast<const float4*>(At + r * D);
        float acc = 0.f;
#pragma unroll
        for (int k4 = 0; k4 < 16; ++k4) {
            float4 a = arow[k4];
            acc = fmaf(a.x, wcol[4 * k4 + 0], acc);
            acc = fmaf(a.y, wcol[4 * k4 + 1], acc);
            acc = fmaf(a.z, wcol[4 * k4 + 2], acc);
            acc = fmaf(a.w, wcol[4 * k4 + 3], acc);
        }
        Zb[(size_t)gr * D + lane] = __float2bfloat16(acc);
    }
}

// ---------------------------------------------------------------------------
// K2: per-unit exclusive scan of bucket-major histG — fully COALESCED.
// SU=2048 elems/block (256 thr x 8); unit totals to partials (<=256).
// ---------------------------------------------------------------------------
__global__ __launch_bounds__(256) void scan_hist(
    const int* __restrict__ histG, int* __restrict__ offsets,
    int* __restrict__ partials, int M)
{
    __shared__ int sh[256];
    const int t    = threadIdx.x;
    const int base = blockIdx.x * SU + t * 8;

    int v[8], ps[8];
#pragma unroll
    for (int k = 0; k < 8; ++k) {
        int m = base + k;
        v[k] = (m < M) ? histG[m] : 0;
    }
    int s = 0;
#pragma unroll
    for (int k = 0; k < 8; ++k) { ps[k] = s; s += v[k]; }
    sh[t] = s;
    __syncthreads();
    for (int off = 1; off < 256; off <<= 1) {
        int x = (t >= off) ? sh[t - off] : 0;
        __syncthreads();
        sh[t] += x;
        __syncthreads();
    }
    const int excl = sh[t] - s;
#pragma unroll
    for (int k = 0; k < 8; ++k)
        offsets[base + k] = excl + ps[k];
    if (t == 255) partials[blockIdx.x] = sh[255];
}

// ---------------------------------------------------------------------------
// K2b: ONE block scans the <=256 unit totals IN PLACE (exclusive prefix).
// Downstream kernels read partials[] directly — no per-block re-scan.
// ---------------------------------------------------------------------------
__global__ __launch_bounds__(256) void scan_partials_k(
    int* __restrict__ partials, int units)
{
    __shared__ int sh[256];
    const int t    = threadIdx.x;
    const int orig = (t < units) ? partials[t] : 0;
    sh[t] = orig;
    __syncthreads();
    for (int off = 1; off < 256; off <<= 1) {
        int x = (t >= off) ? sh[t - off] : 0;
        __syncthreads();
        sh[t] += x;
        __syncthreads();
    }
    if (t < units) partials[t] = sh[t] - orig;   // exclusive
}

// ---------------------------------------------------------------------------
// K3: bucket-grouped scatter.  Recounts its chunk with ds_add_rtn, stages
// records sorted by bucket in LDS, writes runs.  Reads the GLOBAL partials
// prefix (K2b) — no local partials scan.
// rec.x = src(16) | dl(5)<<16 | bkt(11)<<21   (N<65536, NB<2048).
// ---------------------------------------------------------------------------
__global__ __launch_bounds__(256) void scatter_bkt(
    const int*   __restrict__ src,
    const int*   __restrict__ dst,
    const float* __restrict__ w,
    const int*   __restrict__ offsets,
    const int*   __restrict__ partials,   // exclusive prefix (global)
    int2*        __restrict__ csr,
    int E, int NB, int NC)
{
    __shared__ int2 rec[CH];       // 32 KB
    __shared__ int  lcnt[1568];    // 6.3 KB
    __shared__ int  sh[256];

    const int t   = threadIdx.x;
    const int c   = blockIdx.x;
    const int e0  = c * CH;
    const int cnt = min(CH, E - e0);   // multiple of 4

    for (int b = t; b < NB; b += 256) lcnt[b] = 0;
    __syncthreads();

    // load + count-with-return (16 edges/thread, vector loads)
    int2 myrec[16]; int mypos[16];
    const int4*   s4p = reinterpret_cast<const int4*>(src + e0);
    const int4*   d4p = reinterpret_cast<const int4*>(dst + e0);
    const float4* w4p = reinterpret_cast<const float4*>(w + e0);
#pragma unroll
    for (int i = 0; i < 4; ++i) {
        int g = i * 256 + t;
        if (g * 4 < cnt) {
            int4   s4 = s4p[g];
            int4   d4 = d4p[g];
            float4 w4 = w4p[g];
            int b0 = d4.x >> 5, b1 = d4.y >> 5, b2 = d4.z >> 5, b3 = d4.w >> 5;
            myrec[4*i+0] = make_int2(s4.x | ((d4.x & 31) << 16) | (b0 << 21), __float_as_int(w4.x));
            myrec[4*i+1] = make_int2(s4.y | ((d4.y & 31) << 16) | (b1 << 21), __float_as_int(w4.y));
            myrec[4*i+2] = make_int2(s4.z | ((d4.z & 31) << 16) | (b2 << 21), __float_as_int(w4.z));
            myrec[4*i+3] = make_int2(s4.w | ((d4.w & 31) << 16) | (b3 << 21), __float_as_int(w4.w));
            mypos[4*i+0] = atomicAdd(&lcnt[b0], 1);
            mypos[4*i+1] = atomicAdd(&lcnt[b1], 1);
            mypos[4*i+2] = atomicAdd(&lcnt[b2], 1);
            mypos[4*i+3] = atomicAdd(&lcnt[b3], 1);
        } else {
#pragma unroll
            for (int k = 0; k < 4; ++k) mypos[4*i+k] = -1;
        }
    }
    __syncthreads();

    // local exclusive scan of lcnt (7 buckets/thread covers 1792 >= NB)
    int hv[7], ps[7];
    const int hbase = t * 7;
#pragma unroll
    for (int k = 0; k < 7; ++k) {
        int b = hbase + k;
        hv[k] = (b < NB) ? lcnt[b] : 0;
    }
    int s = 0;
#pragma unroll
    for (int k = 0; k < 7; ++k) { ps[k] = s; s += hv[k]; }
    sh[t] = s;
    __syncthreads();
    for (int off = 1; off < 256; off <<= 1) {
        int x = (t >= off) ? sh[t - off] : 0;
        __syncthreads();
        sh[t] += x;
        __syncthreads();
    }
    const int hexcl = sh[t] - s;
    __syncthreads();                       // all reads of lcnt done
#pragma unroll
    for (int k = 0; k < 7; ++k) {
        int b = hbase + k;
        if (b < NB) lcnt[b] = hexcl + ps[k];   // localBase
    }
    __syncthreads();

    // stage records sorted by bucket
#pragma unroll
    for (int k = 0; k < 16; ++k) {
        if (mypos[k] >= 0)
            rec[lcnt[(unsigned)myrec[k].x >> 21] + mypos[k]] = myrec[k];
    }
    __syncthreads();

    // lcnt[b] := globalChunkOff(b,c) - localBase[b]   (global partials read)
#pragma unroll
    for (int k = 0; k < 7; ++k) {
        int b = hbase + k;
        if (b < NB) {
            int m = b * NC + c;
            lcnt[b] = offsets[m] + partials[m >> 11] - lcnt[b];
        }
    }
    __syncthreads();

    for (int j = t; j < cnt; j += 256) {
        int2 rj = rec[j];
        csr[j + lcnt[(unsigned)rj.x >> 21]] = rj;
    }
}

// ---------------------------------------------------------------------------
// K4: one block per 32-node bucket.  Bucket bounds come from the GLOBAL
// offsets+partials (no local scan).  Sort pass edges by node in LDS (int
// atomics + shfl scan), then register-gather with 3-deep per-slot prefetch.
// ---------------------------------------------------------------------------
__global__ __launch_bounds__(256) void aggregate(
    const __hip_bfloat16* __restrict__ Zb,
    const int2* __restrict__ csr,
    const int*  __restrict__ offsets,
    const int*  __restrict__ partials,   // exclusive prefix (global)
    float*      __restrict__ out,
    int N, int NB, int NC)
{
    __shared__ int2 srec[PASS];   // 8 KB
    __shared__ int  hist[BKT];
    __shared__ int  nbase[BKT + 1];

    const int t = threadIdx.x;
    const int b = blockIdx.x;

    const int m0 = b * NC, m1 = m0 + NC;
    const int bStart = offsets[m0] + partials[m0 >> 11];
    const int bEnd   = offsets[m1] + partials[m1 >> 11];

    const int wv = t >> 6, lane = t & 63, slot = lane >> 3, q = lane & 7;
    const int4* Zq = reinterpret_cast<const int4*>(Zb);   // bf16 row = 8 int4

    float4 alo[8], ahi[8];
#pragma unroll
    for (int r = 0; r < 8; ++r) { alo[r] = float4{0,0,0,0}; ahi[r] = float4{0,0,0,0}; }

#define FMA8(LO, HI, WW, ZZ)                                                     \
    do {                                                                         \
        (LO).x = fmaf((WW), __uint_as_float((unsigned)(ZZ).x << 16),        (LO).x); \
        (LO).y = fmaf((WW), __uint_as_float((unsigned)(ZZ).x & 0xFFFF0000u),(LO).y); \
        (LO).z = fmaf((WW), __uint_as_float((unsigned)(ZZ).y << 16),        (LO).z); \
        (LO).w = fmaf((WW), __uint_as_float((unsigned)(ZZ).y & 0xFFFF0000u),(LO).w); \
        (HI).x = fmaf((WW), __uint_as_float((unsigned)(ZZ).z << 16),        (HI).x); \
        (HI).y = fmaf((WW), __uint_as_float((unsigned)(ZZ).z & 0xFFFF0000u),(HI).y); \
        (HI).z = fmaf((WW), __uint_as_float((unsigned)(ZZ).w << 16),        (HI).z); \
        (HI).w = fmaf((WW), __uint_as_float((unsigned)(ZZ).w & 0xFFFF0000u),(HI).w); \
    } while (0)

    for (int cur = bStart; cur < bEnd; cur += PASS) {
        const int cnt = min(PASS, bEnd - cur);
        if (t < BKT) hist[t] = 0;
        __syncthreads();

        int2 myrec[4]; int mypos[4];
#pragma unroll
        for (int k = 0; k < 4; ++k) {
            int j = k * 256 + t;
            if (j < cnt) {
                int2 r2 = csr[cur + j];
                myrec[k] = r2;
                mypos[k] = atomicAdd(&hist[(r2.x >> 16) & (BKT - 1)], 1);
            } else mypos[k] = -1;
        }
        __syncthreads();

        if (t < BKT) {
            int v = hist[t], x = v;
            for (int off = 1; off < BKT; off <<= 1) {
                int y = __shfl_up(x, off, 64);
                if (t >= off) x += y;
            }
            nbase[t] = x - v;
            if (t == BKT - 1) nbase[BKT] = x;
        }
        __syncthreads();

#pragma unroll
        for (int k = 0; k < 4; ++k) {
            if (mypos[k] >= 0)
                srec[nbase[(myrec[k].x >> 16) & (BKT - 1)] + mypos[k]] = myrec[k];
        }
        __syncthreads();

        // gather: wave wv owns nodes [wv*8, wv*8+8), 3-deep prefetched
        for (int r = 0; r < 8; ++r) {
            const int nl = wv * 8 + r;
            const int jb = nbase[nl] + slot;
            const int je = nbase[nl + 1];
            const int j1 = jb + 8, j2 = jb + 16;
            int2 e0 = make_int2(0, 0), e1 = make_int2(0, 0), e2 = make_int2(0, 0);
            if (jb < je) e0 = srec[jb];
            if (j1 < je) e1 = srec[j1];
            if (j2 < je) e2 = srec[j2];
            int4 z0 = make_int4(0,0,0,0), z1 = make_int4(0,0,0,0), z2 = make_int4(0,0,0,0);
            if (jb < je) z0 = Zq[(size_t)(e0.x & 0xFFFF) * 8 + q];
            if (j1 < je) z1 = Zq[(size_t)(e1.x & 0xFFFF) * 8 + q];
            if (j2 < je) z2 = Zq[(size_t)(e2.x & 0xFFFF) * 8 + q];
            FMA8(alo[r], ahi[r], __int_as_float(e0.y), z0);
            FMA8(alo[r], ahi[r], __int_as_float(e1.y), z1);
            FMA8(alo[r], ahi[r], __int_as_float(e2.y), z2);
            for (int j = j2 + 8; j < je; j += 8) {    // tail (deg > 24)
                int2 e = srec[j];
                int4 zz = Zq[(size_t)(e.x & 0xFFFF) * 8 + q];
                FMA8(alo[r], ahi[r], __int_as_float(e.y), zz);
            }
        }
        __syncthreads();
    }

    // reduce the 8 slots + store (8 lanes x 32 B = coalesced 256 B row)
    const int node0 = b * BKT + wv * 8;
#pragma unroll
    for (int r = 0; r < 8; ++r) {
        float4 lo = alo[r], hi = ahi[r];
#pragma unroll
        for (int off = 32; off >= 8; off >>= 1) {
            lo.x += __shfl_down(lo.x, off, 64);
            lo.y += __shfl_down(lo.y, off, 64);
            lo.z += __shfl_down(lo.z, off, 64);
            lo.w += __shfl_down(lo.w, off, 64);
            hi.x += __shfl_down(hi.x, off, 64);
            hi.y += __shfl_down(hi.y, off, 64);
            hi.z += __shfl_down(hi.z, off, 64);
            hi.w += __shfl_down(hi.w, off, 64);
        }
        int node = node0 + r;
        if (lane < 8 && node < N) {
            float4 o0, o1;
            o0.x = fmaxf(lo.x, 0.f); o0.y = fmaxf(lo.y, 0.f);
            o0.z = fmaxf(lo.z, 0.f); o0.w = fmaxf(lo.w, 0.f);
            o1.x = fmaxf(hi.x, 0.f); o1.y = fmaxf(hi.y, 0.f);
            o1.z = fmaxf(hi.z, 0.f); o1.w = fmaxf(hi.w, 0.f);
            float4* orow = reinterpret_cast<float4*>(out) + (size_t)node * 16 + lane * 2;
            orow[0] = o0;
            orow[1] = o1;
        }
    }
#undef FMA8
}

// ---------------------------------------------------------------------------
extern "C" void kernel_launch(void* const* d_in, const int* in_sizes, int n_in,
                              void* d_out, int out_size, void* d_ws, size_t ws_size,
                              hipStream_t stream)
{
    const float* emb  = (const float*)d_in[0];  // [N, 64]
    const int*   esrc = (const int*)  d_in[1];  // [E]
    const int*   edst = (const int*)  d_in[2];  // [E]
    const float* ew   = (const float*)d_in[3];  // [E]
    const float* W    = (const float*)d_in[4];  // [64, 64]
    float*       out  = (float*)d_out;          // [N, 64]

    const int N = in_sizes[0] / D;
    const int E = in_sizes[1];

    const int NB    = (N + BKT - 1) / BKT;   // 1563 buckets
    const int NC    = (E + CH - 1) / CH;     // 196 chunks
    const int M     = NB * NC;               // 306,348
    const int units = (M + SU - 1) / SU;     // 150 <= 256
    const int Mpad  = units * SU;
    const int gemmTiles = (N + 63) / 64;     // 782

    // Workspace (~15.2 MB), all segments 16 B aligned.
    char* p = (char*)d_ws;
    __hip_bfloat16* Zb = (__hip_bfloat16*)p;  p += (size_t)N * D * 2;   // 6.4 MB
    int*  histG    = (int*)p;                 p += (size_t)Mpad * 4;    // 1.2 MB
    int*  offsets  = (int*)p;                 p += (size_t)Mpad * 4;    // 1.2 MB
    int*  partials = (int*)p;                 p += 256 * 4;
    int2* csr      = (int2*)p;                                          // 6.4 MB

    gemm_part<<<gemmTiles + NC, 256, 0, stream>>>(
        emb, W, Zb, edst, histG, N, E, NB, NC, gemmTiles);

    scan_hist<<<units, 256, 0, stream>>>(histG, offsets, partials, M);

    scan_partials_k<<<1, 256, 0, stream>>>(partials, units);

    scatter_bkt<<<NC, 256, 0, stream>>>(
        esrc, edst, ew, offsets, partials, csr, E, NB, NC);

    aggregate<<<NB, 256, 0, stream>>>(
        Zb, csr, offsets, partials, out, N, NB, NC);
}